// Round 3
// baseline (197.746 us; speedup 1.0000x reference)
//
#include <hip/hip_runtime.h>
#include <cstdint>

#define NDIM 80
#define NB (NDIM * NDIM)   // 6400 batches; also elements per batch matrix
#define TOL 0.01f
#define MAXIT 101          // it 0 = prologue (v0, ev0); 1..100 = reference steps

typedef const __attribute__((address_space(1))) void* gas_ptr;
typedef __attribute__((address_space(3))) void* las_ptr;

__global__ void zero_out_kernel(float* __restrict__ out) {
    if (threadIdx.x < NDIM) out[threadIdx.x] = 0.f;
}

// One block per batch b = i*80+j. All three 25.6KB operand tiles are staged
// into LDS via async global_load_lds (1KB per wave-instruction, 15 instrs per
// wave, fire-and-forget). M = wr*rz + rc is built in place over the r_const
// buffer, then the whole power iteration runs out of LDS. 77.5KB LDS -> 2
// blocks/CU; block A's compute hides under block B's staging.
__global__ __launch_bounds__(320) void fused_power_kernel(
    const float* __restrict__ x,
    const float* __restrict__ r_zeros,
    const float* __restrict__ r_const,
    const float* __restrict__ weights_t,
    const float* __restrict__ weights_r,
    float* __restrict__ out)
{
    __shared__ float Ms[NB];    // staged r_const, becomes M in place
    __shared__ float rzs[NB];
    __shared__ float wrs[NB];
    __shared__ float v[NDIM];
    __shared__ float av[NDIM];
    __shared__ float red[2];
    __shared__ float sscale;

    const int t    = threadIdx.x;
    const int wv   = t >> 6;     // wave 0..4
    const int lane = t & 63;
    const int b    = blockIdx.x;
    const size_t base = (size_t)b * NB;

    // Async staging: 25 wave-instructions per array (6400 floats / 256 per
    // instr), 5 per wave per array. LDS dest is wave-uniform base + lane*16B
    // (linear layout, exactly what global_load_lds writes).
    #pragma unroll
    for (int c = 0; c < 5; ++c) {
        const int inst = wv * 5 + c;          // 0..24
        const int foff = inst * 256;          // float offset of this 1KB chunk
        const size_t g = base + foff + lane * 4;
        __builtin_amdgcn_global_load_lds((gas_ptr)(r_const   + g), (las_ptr)&Ms[foff],  16, 0, 0);
        __builtin_amdgcn_global_load_lds((gas_ptr)(r_zeros   + g), (las_ptr)&rzs[foff], 16, 0, 0);
        __builtin_amdgcn_global_load_lds((gas_ptr)(weights_r + g), (las_ptr)&wrs[foff], 16, 0, 0);
    }
    if (t < NDIM) av[t] = 1.0f;   // seed: av = ones, ||av||^2 = 80
    __syncthreads();              // drains vmcnt(0) then barrier (HIP semantics)

    // M = wr*rz + rc, in place. Stride-320 b32 ops: 2 lanes/bank -> free.
    #pragma unroll
    for (int u = 0; u < 20; ++u) {
        const int e = t + 320 * u;
        Ms[e] = fmaf(wrs[e], rzs[e], Ms[e]);
    }
    float n2 = (float)NDIM;
    float ev = 1e30f;             // prologue never "converges"
    __syncthreads();

    const int r = t >> 2;         // row 0..79
    const int q = t & 3;          // column quarter
    const float* Mr = &Ms[r * NDIM + q * 20];   // 16B-aligned row slice

    for (int it = 0; it < MAXIT; ++it) {
        // v = av / ||av||
        const float inv = rsqrtf(n2);
        if (t < NDIM) v[t] = av[t] * inv;
        __syncthreads();                       // v ready

        // av = M v : 5x ds_read_b128 + 20 FMA per thread, quad-combine.
        float p = 0.f;
        const int vq = q * 20;
        #pragma unroll
        for (int k = 0; k < 20; ++k) p = fmaf(Mr[k], v[vq + k], p);
        p += __shfl_xor(p, 1);
        p += __shfl_xor(p, 2);
        if (q == 0) av[r] = p;
        __syncthreads();                       // av ready

        // Fused dual reduction: n2' = ||av||^2, dot = v.av (wave 0 only)
        if (t < 64) {
            float a0 = av[t], v0 = v[t];
            float s2 = a0 * a0;
            float sd = v0 * a0;
            if (t < 16) {
                float a1 = av[t + 64], v1 = v[t + 64];
                s2 = fmaf(a1, a1, s2);
                sd = fmaf(v1, a1, sd);
            }
            #pragma unroll
            for (int o = 32; o > 0; o >>= 1) {
                s2 += __shfl_down(s2, o);
                sd += __shfl_down(sd, o);
            }
            if (t == 0) { red[0] = s2; red[1] = sd; }
        }
        __syncthreads();                       // red ready
        n2 = red[0];
        const float evn = red[1];
        if (fabsf(ev - evn) < TOL) break;      // uniform across block
        ev = evn;
    }

    // scale = x[b]*wt[b]*M-diag-source / v[i];  out[k] += v[k]*scale
    if (t == 0) {
        const int i_idx = b / NDIM;
        const float tval = x[b] * weights_t[b]
                         * Ms[0 * 0 + 0];      // placeholder, replaced below
        (void)tval;
        const float rc_diag = r_const[base + (size_t)i_idx * NDIM + i_idx];
        sscale = x[b] * weights_t[b] * rc_diag / v[i_idx];
    }
    __syncthreads();
    if (t < NDIM) atomicAdd(&out[t], v[t] * sscale);
}

extern "C" void kernel_launch(void* const* d_in, const int* in_sizes, int n_in,
                              void* d_out, int out_size, void* d_ws, size_t ws_size,
                              hipStream_t stream) {
    const float* x  = (const float*)d_in[0];   // (80,80)
    const float* rz = (const float*)d_in[1];   // (80,80,80,80)
    const float* rc = (const float*)d_in[2];   // (80,80,80,80)
    const float* wt = (const float*)d_in[3];   // (80,80)
    const float* wr = (const float*)d_in[4];   // (80,80,80,80)
    float* out = (float*)d_out;                // (80,)

    hipLaunchKernelGGL(zero_out_kernel, dim3(1), dim3(128), 0, stream, out);
    hipLaunchKernelGGL(fused_power_kernel, dim3(NB), dim3(320), 0, stream,
                       x, rz, rc, wt, wr, out);
}

// Round 4
// 100.170 us; speedup vs baseline: 1.9741x; 1.9741x over previous
//
#include <hip/hip_runtime.h>

#define NDIM 80
#define NB (NDIM * NDIM)   // 6400 batches; also elements per batch matrix
#define TOL 0.01f
#define MAXIT 101          // it 0 = prologue (v0, ev0); 1..100 = reference steps

typedef const __attribute__((address_space(1))) void* gas_ptr;
typedef __attribute__((address_space(3))) void* las_ptr;

// One block per batch b = i*80+j.
// r_const -> LDS directly (async global_load_lds, no VGPR round trip).
// r_zeros/weights_r -> registers via lane-consecutive dwordx4 (coalesced),
// multiplied into prod[5] (20 VGPRs across one barrier), then FMA'd into M
// in place. LDS = 26.3 KB -> 6 blocks/CU (30 waves): block A's power loop
// hides under blocks B..F's staging.
__global__ __launch_bounds__(320, 8) void fused_power_kernel(
    const float* __restrict__ x,
    const float* __restrict__ r_zeros,
    const float* __restrict__ r_const,
    const float* __restrict__ weights_t,
    const float* __restrict__ weights_r,
    float* __restrict__ contrib)
{
    __shared__ float Ms[NB];    // staged r_const, becomes M in place (25.6 KB)
    __shared__ float v[NDIM];
    __shared__ float av[NDIM];
    __shared__ float red[2];
    __shared__ float sscale;

    const int t    = threadIdx.x;
    const int wv   = t >> 6;     // wave 0..4
    const int lane = t & 63;
    const int b    = blockIdx.x;
    const size_t base = (size_t)b * NB;

    // Async: 25 x 1KB chunks of r_const -> Ms (5 per wave, fire-and-forget).
    #pragma unroll
    for (int c = 0; c < 5; ++c) {
        const int foff = (wv * 5 + c) * 256;   // float offset of this 1KB chunk
        __builtin_amdgcn_global_load_lds((gas_ptr)(r_const + base + foff + lane * 4),
                                         (las_ptr)&Ms[foff], 16, 0, 0);
    }

    // rz*wr into registers; float4 f = t + 320u -> byte 16*t stride: perfectly
    // coalesced dwordx4, issued back-to-back for MLP.
    float4 prod[5];
    {
        const float4* rz4 = reinterpret_cast<const float4*>(r_zeros + base);
        const float4* wr4 = reinterpret_cast<const float4*>(weights_r + base);
        #pragma unroll
        for (int u = 0; u < 5; ++u) {
            const float4 a = rz4[t + 320 * u];
            const float4 w = wr4[t + 320 * u];
            prod[u].x = w.x * a.x;
            prod[u].y = w.y * a.y;
            prod[u].z = w.z * a.z;
            prod[u].w = w.w * a.w;
        }
    }
    if (t < NDIM) av[t] = 1.0f;   // seed: av = ones, ||av||^2 = 80
    __syncthreads();              // drains vmcnt(0): rc in LDS, prods ready

    // M = rc + wr*rz, in place. b128 RMW, conflict-free (min 8-way aliasing).
    #pragma unroll
    for (int u = 0; u < 5; ++u) {
        float4* p4 = reinterpret_cast<float4*>(&Ms[4 * (t + 320 * u)]);
        float4 cc = *p4;
        cc.x += prod[u].x;
        cc.y += prod[u].y;
        cc.z += prod[u].z;
        cc.w += prod[u].w;
        *p4 = cc;
    }
    float n2 = (float)NDIM;
    float ev = 1e30f;             // prologue never "converges"
    __syncthreads();

    const int r  = t >> 2;        // row 0..79
    const int q  = t & 3;         // column quarter
    const int vq = q * 20;
    const float4* Mr4 = reinterpret_cast<const float4*>(&Ms[r * NDIM + vq]);
    const float4* vv4 = reinterpret_cast<const float4*>(&v[vq]);

    for (int it = 0; it < MAXIT; ++it) {
        // v = av / ||av||
        const float inv = rsqrtf(n2);
        if (t < NDIM) v[t] = av[t] * inv;
        __syncthreads();                       // v ready

        // av = M v : 5x ds_read_b128 (M) + 5x b128 broadcast (v), 20 FMA.
        float p = 0.f;
        #pragma unroll
        for (int u = 0; u < 5; ++u) {
            const float4 mm = Mr4[u];
            const float4 xv = vv4[u];
            p = fmaf(mm.x, xv.x, p);
            p = fmaf(mm.y, xv.y, p);
            p = fmaf(mm.z, xv.z, p);
            p = fmaf(mm.w, xv.w, p);
        }
        p += __shfl_xor(p, 1);
        p += __shfl_xor(p, 2);
        if (q == 0) av[r] = p;
        __syncthreads();                       // av ready

        // Fused dual reduction: n2' = ||av||^2, dot = v.av (wave 0 only)
        if (t < 64) {
            float a0 = av[t], v0 = v[t];
            float s2 = a0 * a0;
            float sd = v0 * a0;
            if (t < 16) {
                float a1 = av[t + 64], v1 = v[t + 64];
                s2 = fmaf(a1, a1, s2);
                sd = fmaf(v1, a1, sd);
            }
            #pragma unroll
            for (int o = 32; o > 0; o >>= 1) {
                s2 += __shfl_down(s2, o);
                sd += __shfl_down(sd, o);
            }
            if (t == 0) { red[0] = s2; red[1] = sd; }
        }
        __syncthreads();                       // red ready
        n2 = red[0];
        const float evn = red[1];
        if (fabsf(ev - evn) < TOL) break;      // uniform across block
        ev = evn;
    }

    // contrib[b][k] = v[k] * x[b]*wt[b]*rc[i,j,i,i] / v[i]
    if (t == 0) {
        const int i_idx = b / NDIM;
        const float rc_diag = r_const[base + (size_t)i_idx * NDIM + i_idx];
        sscale = x[b] * weights_t[b] * rc_diag / v[i_idx];
    }
    __syncthreads();
    if (t < NDIM) contrib[(size_t)b * NDIM + t] = v[t] * sscale;
}

// out[k] = sum_b contrib[b][k]; fixed-order tree -> deterministic.
__global__ __launch_bounds__(256) void reduce_kernel(
    const float* __restrict__ contrib,
    float* __restrict__ out)
{
    __shared__ float s[256];
    const int k = blockIdx.x;
    const int t = threadIdx.x;
    float acc = 0.f;
    for (int b = t; b < NB; b += 256)
        acc += contrib[(size_t)b * NDIM + k];
    s[t] = acc;
    __syncthreads();
    for (int o = 128; o > 0; o >>= 1) {
        if (t < o) s[t] += s[t + o];
        __syncthreads();
    }
    if (t == 0) out[k] = s[0];
}

extern "C" void kernel_launch(void* const* d_in, const int* in_sizes, int n_in,
                              void* d_out, int out_size, void* d_ws, size_t ws_size,
                              hipStream_t stream) {
    const float* x  = (const float*)d_in[0];   // (80,80)
    const float* rz = (const float*)d_in[1];   // (80,80,80,80)
    const float* rc = (const float*)d_in[2];   // (80,80,80,80)
    const float* wt = (const float*)d_in[3];   // (80,80)
    const float* wr = (const float*)d_in[4];   // (80,80,80,80)
    float* out = (float*)d_out;                // (80,)

    float* contrib = (float*)d_ws;             // 6400*80 floats = 2 MB

    hipLaunchKernelGGL(fused_power_kernel, dim3(NB), dim3(320), 0, stream,
                       x, rz, rc, wt, wr, contrib);
    hipLaunchKernelGGL(reduce_kernel, dim3(NDIM), dim3(256), 0, stream,
                       contrib, out);
}